// Round 1
// baseline (2229.793 us; speedup 1.0000x reference)
//
#include <hip/hip_runtime.h>
#include <math.h>

// ---- problem constants ----
#define BH 32          // B*H
#define NSEQ 4096
#define EDIM 64
#define MDIM 128
#define NHASH 2
#define NBUCK 32
#define BSZC 128
#define BB 4
#define HH 8
#define DD 512

// ---- workspace layout (bytes) ----
static constexpr size_t OFF_SQQ  = 0;
static constexpr size_t SZ_ROWD  = (size_t)BH*NSEQ*8;
static constexpr size_t OFF_SQK  = OFF_SQQ + SZ_ROWD;
static constexpr size_t OFF_QH   = OFF_SQK + SZ_ROWD;
static constexpr size_t SZ_HASH  = (size_t)NHASH*BH*NSEQ*8;
static constexpr size_t OFF_KH   = OFF_QH + SZ_HASH;
static constexpr size_t OFF_MAXQ = OFF_KH + SZ_HASH;          // 32 doubles
static constexpr size_t OFF_MAXK = OFF_MAXQ + 256;
static constexpr size_t OFF_KLS  = OFF_MAXK + 256;            // 32 uint (ordered-float enc)
static constexpr size_t OFF_QPOS = OFF_KLS + 256;
static constexpr size_t SZ_POS   = (size_t)NHASH*BH*NSEQ*4;
static constexpr size_t OFF_KPOS = OFF_QPOS + SZ_POS;
static constexpr size_t OFF_QREV = OFF_KPOS + SZ_POS;
static constexpr size_t OFF_KREV = OFF_QREV + SZ_POS;
static constexpr size_t OFF_QP   = OFF_KREV + SZ_POS;         // bh*N*M f32
static constexpr size_t SZ_PRIME = (size_t)BH*NSEQ*MDIM*4;
static constexpr size_t OFF_KP   = OFF_QP + SZ_PRIME;
static constexpr size_t OFF_QLS  = OFF_KP + SZ_PRIME;         // bh*N f32
static constexpr size_t OFF_KV   = OFF_QLS + (size_t)BH*NSEQ*4;   // bh*M*E f32
static constexpr size_t OFF_KSUM = OFF_KV + (size_t)BH*MDIM*EDIM*4;
static constexpr size_t OFF_O    = OFF_KSUM + (size_t)BH*MDIM*4;  // NH*bh*N*E f32
static constexpr size_t OFF_LSE  = OFF_O + (size_t)NHASH*BH*NSEQ*EDIM*4;
static constexpr size_t OFF_DSUM = OFF_LSE + (size_t)NHASH*BH*NSEQ*4;
static constexpr size_t OFF_OUTN = OFF_DSUM + (size_t)NHASH*BH*NSEQ*4;  // B*N*D f32

#define SQRT_TEMP 0.3535533905932738f
#define HALF_LOG_M 2.4260151319598085f
#define LN2F 0.6931471805599453f

__device__ __forceinline__ unsigned encF(float f){
  unsigned u = __float_as_uint(f);
  return (u & 0x80000000u) ? ~u : (u | 0x80000000u);
}
__device__ __forceinline__ float decF(unsigned e){
  return __uint_as_float((e & 0x80000000u) ? (e ^ 0x80000000u) : ~e);
}

// ---------------- init ----------------
__global__ void k_init(char* __restrict__ ws){
  int idx = blockIdx.x*256 + threadIdx.x;
  if (idx < BH*MDIM*EDIM) ((float*)(ws+OFF_KV))[idx] = 0.0f;
  if (idx < BH){
    ((unsigned long long*)(ws+OFF_MAXQ))[idx] = 0ull;
    ((unsigned long long*)(ws+OFF_MAXK))[idx] = 0ull;
    ((unsigned*)(ws+OFF_KLS))[idx] = encF(-INFINITY);
  }
}

// ---------------- per-position squared norms + per-bh max ----------------
__global__ __launch_bounds__(256) void k_sumsq(const float* __restrict__ q, const float* __restrict__ k,
                                               char* __restrict__ ws){
  int p = blockIdx.x*256 + threadIdx.x;
  int bh = p >> 12, t = p & (NSEQ-1);
  int bo = bh >> 3, hh = bh & 7;
  const float* qr = q + ((size_t)bo*NSEQ + t)*DD + hh*EDIM;
  const float* kr = k + ((size_t)bo*NSEQ + t)*DD + hh*EDIM;
  double sq = 0.0, sk = 0.0;
  for (int e = 0; e < EDIM; e++){
    double a = qr[e]; sq = fma(a, a, sq);
    double b = kr[e]; sk = fma(b, b, sk);
  }
  ((double*)(ws+OFF_SQQ))[p] = sq;
  ((double*)(ws+OFF_SQK))[p] = sk;
  int lane = threadIdx.x & 63, wid = threadIdx.x >> 6;
  double mq = sq, mk = sk;
  for (int o = 32; o; o >>= 1){ mq = fmax(mq, __shfl_xor(mq, o)); mk = fmax(mk, __shfl_xor(mk, o)); }
  __shared__ double smq[4], smk[4];
  if (!lane){ smq[wid] = mq; smk[wid] = mk; }
  __syncthreads();
  if (!threadIdx.x){
    double a = fmax(fmax(smq[0], smq[1]), fmax(smq[2], smq[3]));
    double b = fmax(fmax(smk[0], smk[1]), fmax(smk[2], smk[3]));
    atomicMax((unsigned long long*)(ws+OFF_MAXQ) + bh, (unsigned long long)__double_as_longlong(a));
    atomicMax((unsigned long long*)(ws+OFF_MAXK) + bh, (unsigned long long)__double_as_longlong(b));
  }
}

// ---------------- E2LSH hashes in fp64 (ordering fidelity) ----------------
__global__ __launch_bounds__(256) void k_hash(const float* __restrict__ query, const float* __restrict__ key,
                                              const float* __restrict__ alpha, const float* __restrict__ beta,
                                              char* __restrict__ ws){
  int p = blockIdx.x*256 + threadIdx.x;
  int bh = p >> 12, t = p & (NSEQ-1);
  int bo = bh >> 3, hh = bh & 7;
  const float* qr = query + ((size_t)bo*NSEQ + t)*DD + hh*EDIM;
  const float* kr = key   + ((size_t)bo*NSEQ + t)*DD + hh*EDIM;
  double mqk = ((const double*)(ws+OFF_MAXQ))[bh] + ((const double*)(ws+OFF_MAXK))[bh];
  double sq  = ((const double*)(ws+OFF_SQQ))[p];
  double sk  = ((const double*)(ws+OFF_SQK))[p];
  double extq = sqrt(fmax(mqk - sq, 0.0));
  double extk = sqrt(fmax(mqk - sk, 0.0));
  double a0=0, a1=0, c0=0, c1=0;
  for (int e = 0; e < EDIM; e++){
    double qv = qr[e], kv = kr[e];
    double al0 = alpha[e*2+0], al1 = alpha[e*2+1];
    a0 = fma(qv, al0, a0); a1 = fma(qv, al1, a1);
    c0 = fma(kv, al0, c0); c1 = fma(kv, al1, c1);
  }
  a0 += extq * (double)alpha[64*2+0]; a1 += extq * (double)alpha[64*2+1];
  c0 += extk * (double)alpha[65*2+0]; c1 += extk * (double)alpha[65*2+1];
  double b0 = beta[0], b1 = beta[1];
  double* qh = (double*)(ws+OFF_QH);
  double* kh = (double*)(ws+OFF_KH);
  qh[p] = a0 + b0; qh[(size_t)BH*NSEQ + p] = a1 + b1;
  kh[p] = c0 + b0; kh[(size_t)BH*NSEQ + p] = c1 + b1;
}

// ---------------- bitonic argsort of 4096 per (hash, bh) row ----------------
__global__ __launch_bounds__(256) void k_sort(char* __restrict__ ws){
  int row = blockIdx.x;                 // 0..63 q rows, 64..127 k rows
  bool isK = row >= NHASH*BH;
  int r = isK ? row - NHASH*BH : row;
  const double* hash = (const double*)(ws + (isK ? OFF_KH : OFF_QH)) + (size_t)r*NSEQ;
  int* pos = (int*)(ws + (isK ? OFF_KPOS : OFF_QPOS)) + (size_t)r*NSEQ;
  int* rev = (int*)(ws + (isK ? OFF_KREV : OFF_QREV)) + (size_t)r*NSEQ;
  __shared__ double ks_[NSEQ];
  __shared__ int    is_[NSEQ];
  for (int i = threadIdx.x; i < NSEQ; i += 256){ ks_[i] = hash[i]; is_[i] = i; }
  __syncthreads();
  for (int k = 2; k <= NSEQ; k <<= 1){
    for (int j = k >> 1; j > 0; j >>= 1){
      for (int i = threadIdx.x; i < NSEQ; i += 256){
        int ixj = i ^ j;
        if (ixj > i){
          double a = ks_[i], b = ks_[ixj];
          bool up = ((i & k) == 0);
          if ((a > b) == up){
            ks_[i] = b; ks_[ixj] = a;
            int tmp = is_[i]; is_[i] = is_[ixj]; is_[ixj] = tmp;
          }
        }
      }
      __syncthreads();
    }
  }
  for (int i = threadIdx.x; i < NSEQ; i += 256){ int t = is_[i]; pos[i] = t; rev[t] = i; }
}

// ---------------- Performer features: query (per-position stab, fused exp) ----------------
__global__ __launch_bounds__(256) void k_featq(const float* __restrict__ query, const float* __restrict__ projW,
                                               char* __restrict__ ws){
  __shared__ float WT[EDIM*MDIM];     // WT[e*128+m] = W[m][e]
  __shared__ float s_q[4][EDIM];
  int tid = threadIdx.x, lane = tid & 63, wid = tid >> 6;
  for (int l = tid; l < EDIM*MDIM; l += 256) WT[l] = projW[(l & 127)*EDIM + (l >> 7)];
  __syncthreads();
  float* qp  = (float*)(ws+OFF_QP);
  float* qls = (float*)(ws+OFF_QLS);
  for (int it = 0; it < 16; it++){
    int p = blockIdx.x*64 + wid*16 + it;
    int bh = p >> 12, t = p & (NSEQ-1), bo = bh >> 3, hh = bh & 7;
    float xv = query[((size_t)bo*NSEQ + t)*DD + hh*EDIM + lane] * SQRT_TEMP;
    s_q[wid][lane] = xv;
    float ss = xv*xv;
    for (int o = 32; o; o >>= 1) ss += __shfl_xor(ss, o);
    __syncthreads();
    float a0 = 0.f, a1 = 0.f;
    for (int e = 0; e < EDIM; e++){
      float qe = s_q[wid][e];
      a0 = fmaf(qe, WT[e*128 + lane], a0);
      a1 = fmaf(qe, WT[e*128 + 64 + lane], a1);
    }
    float c = 0.5f*ss + HALF_LOG_M;
    float lp0 = a0 - c, lp1 = a1 - c;
    float mx = fmaxf(lp0, lp1);
    for (int o = 32; o; o >>= 1) mx = fmaxf(mx, __shfl_xor(mx, o));
    size_t base = (size_t)p*MDIM;
    qp[base + lane]      = expf(lp0 - mx);
    qp[base + 64 + lane] = expf(lp1 - mx);
    if (!lane) qls[p] = mx;
    __syncthreads();
  }
}

// ---------------- Performer features: key (raw log_phi + global max) ----------------
__global__ __launch_bounds__(256) void k_featk(const float* __restrict__ key, const float* __restrict__ projW,
                                               char* __restrict__ ws){
  __shared__ float WT[EDIM*MDIM];
  __shared__ float s_q[4][EDIM];
  int tid = threadIdx.x, lane = tid & 63, wid = tid >> 6;
  for (int l = tid; l < EDIM*MDIM; l += 256) WT[l] = projW[(l & 127)*EDIM + (l >> 7)];
  __syncthreads();
  float* kp = (float*)(ws+OFF_KP);
  int bh0 = (blockIdx.x*64) >> 12;
  float bmax = -INFINITY;
  for (int it = 0; it < 16; it++){
    int p = blockIdx.x*64 + wid*16 + it;
    int bh = p >> 12, t = p & (NSEQ-1), bo = bh >> 3, hh = bh & 7;
    float xv = key[((size_t)bo*NSEQ + t)*DD + hh*EDIM + lane] * SQRT_TEMP;
    s_q[wid][lane] = xv;
    float ss = xv*xv;
    for (int o = 32; o; o >>= 1) ss += __shfl_xor(ss, o);
    __syncthreads();
    float a0 = 0.f, a1 = 0.f;
    for (int e = 0; e < EDIM; e++){
      float qe = s_q[wid][e];
      a0 = fmaf(qe, WT[e*128 + lane], a0);
      a1 = fmaf(qe, WT[e*128 + 64 + lane], a1);
    }
    float c = 0.5f*ss + HALF_LOG_M;
    float lp0 = a0 - c, lp1 = a1 - c;
    size_t base = (size_t)p*MDIM;
    kp[base + lane]      = lp0;
    kp[base + 64 + lane] = lp1;
    float mx = fmaxf(lp0, lp1);
    for (int o = 32; o; o >>= 1) mx = fmaxf(mx, __shfl_xor(mx, o));
    bmax = fmaxf(bmax, mx);
    __syncthreads();
  }
  __shared__ float wm[4];
  if (!lane) wm[wid] = bmax;
  __syncthreads();
  if (!tid){
    float m = fmaxf(fmaxf(wm[0], wm[1]), fmaxf(wm[2], wm[3]));
    atomicMax((unsigned*)(ws+OFF_KLS) + bh0, encF(m));
  }
}

// ---------------- k_prime = exp(log_phi - stab) ----------------
__global__ void k_expk(char* __restrict__ ws){
  size_t idx = (size_t)blockIdx.x*256 + threadIdx.x;       // over bh*N*M/4
  float4* kp = (float4*)(ws+OFF_KP);
  int b = (int)(idx >> 17);                                // N*M/4 = 2^17 per bh
  float stab = decF(((const unsigned*)(ws+OFF_KLS))[b]);
  float4 v = kp[idx];
  v.x = expf(v.x - stab); v.y = expf(v.y - stab);
  v.z = expf(v.z - stab); v.w = expf(v.w - stab);
  kp[idx] = v;
}

// ---------------- kv[b][m][d] = sum_s kprime[s][m] * v[s][d] ----------------
__global__ __launch_bounds__(256) void k_kv(const float* __restrict__ value, char* __restrict__ ws){
  int b = blockIdx.x >> 3;
  int chunk = blockIdx.x & 7;
  int bo = b >> 3, hh = b & 7;
  const float* kp = (const float*)(ws+OFF_KP) + (size_t)b*NSEQ*MDIM;
  __shared__ float skp[16*MDIM];
  __shared__ float sv[16*EDIM];
  int d = threadIdx.x & 63, mg = threadIdx.x >> 6;  // mg == wave id
  float acc[32];
  #pragma unroll
  for (int i = 0; i < 32; i++) acc[i] = 0.f;
  for (int s0 = chunk*512; s0 < chunk*512 + 512; s0 += 16){
    __syncthreads();
    for (int l = threadIdx.x; l < 16*MDIM; l += 256)
      skp[l] = kp[(size_t)(s0 + (l >> 7))*MDIM + (l & 127)];
    for (int l = threadIdx.x; l < 16*EDIM; l += 256)
      sv[l] = value[((size_t)bo*NSEQ + s0 + (l >> 6))*DD + hh*EDIM + (l & 63)];
    __syncthreads();
    for (int ss = 0; ss < 16; ss++){
      float vv = sv[ss*64 + d];
      #pragma unroll
      for (int mi = 0; mi < 32; mi++)
        acc[mi] = fmaf(skp[ss*128 + mg*32 + mi], vv, acc[mi]);
    }
  }
  float* kv = (float*)(ws+OFF_KV) + (size_t)b*MDIM*EDIM;
  #pragma unroll
  for (int mi = 0; mi < 32; mi++) atomicAdd(&kv[(mg*32 + mi)*64 + d], acc[mi]);
}

// ---------------- ksum[b][m] = sum_s kprime[s][m] ----------------
__global__ __launch_bounds__(256) void k_ksum(char* __restrict__ ws){
  int b = blockIdx.x;
  int m = threadIdx.x & 127, sg = threadIdx.x >> 7;
  const float* kp = (const float*)(ws+OFF_KP) + (size_t)b*NSEQ*MDIM;
  float acc = 0.f;
  for (int s = sg; s < NSEQ; s += 2) acc += kp[(size_t)s*MDIM + m];
  __shared__ float red[256];
  red[threadIdx.x] = acc;
  __syncthreads();
  if (!sg) ((float*)(ws+OFF_KSUM))[b*MDIM + m] = red[m] + red[128 + m];
}

// ---------------- bucketed exact correction (scatters unsorted) ----------------
__global__ __launch_bounds__(256) void k_bucket(const float* __restrict__ query, const float* __restrict__ key,
                                                const float* __restrict__ value, char* __restrict__ ws){
  __shared__ float s_kT[EDIM*129];     // [e][j], padded
  __shared__ float s_kpT[MDIM*129];    // [m][j], padded
  __shared__ float s_v[BSZC*EDIM];     // [j][d]
  __shared__ int   s_tk[BSZC];
  __shared__ int   s_kb[BSZC*2];
  __shared__ float s_qrow[4][4*EDIM];
  __shared__ float s_qprow[4][4*MDIM];
  __shared__ float s_drow[4][4*BSZC];

  int blk = blockIdx.x;
  int h = blk >> 10;           // / (BH*NBUCK)
  int b = (blk >> 5) & 31;
  int n = blk & 31;
  int tid = threadIdx.x, lane = tid & 63, wid = tid >> 6;
  int bo = b >> 3, hh = b & 7;

  const int* kpos = (const int*)(ws+OFF_KPOS) + ((size_t)h*BH + b)*NSEQ + n*BSZC;
  const int* qpos = (const int*)(ws+OFF_QPOS) + ((size_t)h*BH + b)*NSEQ + n*BSZC;
  const int* qrev0 = (const int*)(ws+OFF_QREV) + (size_t)b*NSEQ;
  const int* qrev1 = (const int*)(ws+OFF_QREV) + ((size_t)BH + b)*NSEQ;
  const int* krev0 = (const int*)(ws+OFF_KREV) + (size_t)b*NSEQ;
  const int* krev1 = (const int*)(ws+OFF_KREV) + ((size_t)BH + b)*NSEQ;
  const float* qp_g = (const float*)(ws+OFF_QP) + (size_t)b*NSEQ*MDIM;
  const float* kp_g = (const float*)(ws+OFF_KP) + (size_t)b*NSEQ*MDIM;
  const float* qls  = (const float*)(ws+OFF_QLS) + (size_t)b*NSEQ;
  float klsb = decF(((const unsigned*)(ws+OFF_KLS))[b]);

  if (tid < BSZC) s_tk[tid] = kpos[tid];
  __syncthreads();
  { int j = tid & 127, hp = tid >> 7;
    int t = s_tk[j];
    s_kb[j*2 + hp] = ((hp ? krev1 : krev0)[t]) >> 7; }
  for (int l = tid; l < BSZC*EDIM; l += 256){
    int j = l >> 6, e = l & 63; int t = s_tk[j];
    s_kT[e*129 + j] = key[((size_t)bo*NSEQ + t)*DD + hh*EDIM + e];
  }
  for (int l = tid; l < BSZC*MDIM; l += 256){
    int j = l >> 7, m = l & 127; int t = s_tk[j];
    s_kpT[m*129 + j] = kp_g[(size_t)t*MDIM + m];
  }
  for (int l = tid; l < BSZC*EDIM; l += 256){
    int j = l >> 6, e = l & 63; int t = s_tk[j];
    s_v[j*64 + e] = value[((size_t)bo*NSEQ + t)*DD + hh*EDIM + e];
  }
  __syncthreads();

  float* o_g   = (float*)(ws+OFF_O)    + ((size_t)h*BH + b)*NSEQ*EDIM;
  float* lse_g = (float*)(ws+OFF_LSE)  + ((size_t)h*BH + b)*NSEQ;
  float* dsm_g = (float*)(ws+OFF_DSUM) + ((size_t)h*BH + b)*NSEQ;

  int kb00 = s_kb[lane*2+0],       kb01 = s_kb[lane*2+1];
  int kb10 = s_kb[(lane+64)*2+0],  kb11 = s_kb[(lane+64)*2+1];

  for (int q8 = 0; q8 < 8; q8++){
    int i0 = wid*32 + q8*4;
    int tq[4]; float pls[4]; int qb0[4], qb1[4];
    #pragma unroll
    for (int r = 0; r < 4; r++){
      int t = qpos[i0 + r]; tq[r] = t;
      pls[r] = qls[t] + klsb;
      qb0[r] = qrev0[t] >> 7;
      qb1[r] = qrev1[t] >> 7;
      s_qrow[wid][r*64 + lane]        = query[((size_t)bo*NSEQ + t)*DD + hh*EDIM + lane];
      s_qprow[wid][r*128 + lane]      = qp_g[(size_t)t*MDIM + lane];
      s_qprow[wid][r*128 + 64 + lane] = qp_g[(size_t)t*MDIM + 64 + lane];
    }
    __syncthreads();
    float ai0[4] = {0,0,0,0}, ai1[4] = {0,0,0,0};
    for (int e = 0; e < 64; e++){
      float k0 = s_kT[e*129 + lane], k1 = s_kT[e*129 + 64 + lane];
      #pragma unroll
      for (int r = 0; r < 4; r++){
        float qe = s_qrow[wid][r*64 + e];
        ai0[r] = fmaf(qe, k0, ai0[r]); ai1[r] = fmaf(qe, k1, ai1[r]);
      }
    }
    float ap0[4] = {0,0,0,0}, ap1[4] = {0,0,0,0};
    for (int m = 0; m < 128; m++){
      float p0 = s_kpT[m*129 + lane], p1 = s_kpT[m*129 + 64 + lane];
      #pragma unroll
      for (int r = 0; r < 4; r++){
        float qm = s_qprow[wid][r*128 + m];
        ap0[r] = fmaf(qm, p0, ap0[r]); ap1[r] = fmaf(qm, p1, ap1[r]);
      }
    }
    float Ls[4], dsv[4];
    #pragma unroll
    for (int r = 0; r < 4; r++){
      int dup0 = (qb0[r] == kb00) + (qb1[r] == kb01);
      int dup1 = (qb0[r] == kb10) + (qb1[r] == kb11);
      float in0 = ai0[r]*0.125f - (dup0 == 2 ? LN2F : 0.f);
      float in1 = ai1[r]*0.125f - (dup1 == 2 ? LN2F : 0.f);
      float dp0 = ap0[r]*(dup0 == 2 ? 0.5f : 1.f);
      float dp1 = ap1[r]*(dup1 == 2 ? 0.5f : 1.f);
      float mx = fmaxf(in0, in1);
      for (int o = 32; o; o >>= 1) mx = fmaxf(mx, __shfl_xor(mx, o));
      float L = fmaxf(mx, pls[r]); Ls[r] = L;
      float ep = expf(pls[r] - L);
      float d0 = expf(in0 - L) - dp0*ep;
      float d1 = expf(in1 - L) - dp1*ep;
      s_drow[wid][r*128 + lane]      = d0;
      s_drow[wid][r*128 + 64 + lane] = d1;
      float s = d0 + d1;
      for (int o = 32; o; o >>= 1) s += __shfl_xor(s, o);
      dsv[r] = s;
    }
    __syncthreads();
    float ao[4] = {0,0,0,0};
    for (int j = 0; j < 128; j++){
      float vv = s_v[j*64 + lane];
      #pragma unroll
      for (int r = 0; r < 4; r++) ao[r] = fmaf(s_drow[wid][r*128 + j], vv, ao[r]);
    }
    #pragma unroll
    for (int r = 0; r < 4; r++){
      o_g[(size_t)tq[r]*EDIM + lane] = ao[r];
      if (!lane){ lse_g[tq[r]] = Ls[r]; dsm_g[tq[r]] = dsv[r]; }
    }
    __syncthreads();
  }
}

// ---------------- combine (logsumexp over hashes + Performer branch) ----------------
__global__ __launch_bounds__(256) void k_combine(char* __restrict__ ws){
  int b = blockIdx.x >> 6;
  int chunk = blockIdx.x & 63;
  int tid = threadIdx.x, lane = tid & 63, wid = tid >> 6;
  __shared__ float s_kv[MDIM*EDIM];
  __shared__ float s_ks[MDIM];
  __shared__ float s_qp[4][MDIM];
  const float* kv = (const float*)(ws+OFF_KV) + (size_t)b*MDIM*EDIM;
  for (int l = tid; l < MDIM*EDIM; l += 256) s_kv[l] = kv[l];
  if (tid < MDIM) s_ks[tid] = ((const float*)(ws+OFF_KSUM))[b*MDIM + tid];
  __syncthreads();
  const float* qp_g  = (const float*)(ws+OFF_QP) + (size_t)b*NSEQ*MDIM;
  const float* qls   = (const float*)(ws+OFF_QLS) + (size_t)b*NSEQ;
  const float* lse_g = (const float*)(ws+OFF_LSE);
  const float* dsm_g = (const float*)(ws+OFF_DSUM);
  const float* o_g   = (const float*)(ws+OFF_O);
  float* outn = (float*)(ws+OFF_OUTN);
  float klsb = decF(((const unsigned*)(ws+OFF_KLS))[b]);
  int bo = b >> 3, hh = b & 7;
  for (int it = 0; it < 16; it++){
    int t = chunk*64 + wid*16 + it;
    float qp0 = qp_g[(size_t)t*MDIM + lane];
    float qp1 = qp_g[(size_t)t*MDIM + 64 + lane];
    s_qp[wid][lane] = qp0; s_qp[wid][64 + lane] = qp1;
    __syncthreads();
    float qkv = 0.f;
    for (int m = 0; m < 128; m++) qkv = fmaf(s_qp[wid][m], s_kv[m*64 + lane], qkv);
    float qk1 = qp0*s_ks[lane] + qp1*s_ks[64 + lane];
    for (int o = 32; o; o >>= 1) qk1 += __shfl_xor(qk1, o);
    size_t pidx = (size_t)b*NSEQ + t;
    float l0 = lse_g[pidx], l1 = lse_g[(size_t)BH*NSEQ + pidx];
    float mx = fmaxf(l0, l1);
    float nls = mx + logf(expf(l0 - mx) + expf(l1 - mx));
    float p0 = expf(l0 - nls), p1 = expf(l1 - nls);
    float ps = expf(qls[t] + klsb - nls);
    float o0 = o_g[pidx*EDIM + lane];
    float o1 = o_g[((size_t)BH*NSEQ + pidx)*EDIM + lane];
    float ds0 = dsm_g[pidx], ds1 = dsm_g[(size_t)BH*NSEQ + pidx];
    float outv = o0*p0 + o1*p1 + qkv*ps;
    float nrm  = ds0*p0 + ds1*p1 + qk1*ps;
    outn[((size_t)bo*NSEQ + t)*DD + hh*EDIM + lane] = outv / fmaxf(nrm, 1e-6f);
    __syncthreads();
  }
}

// ---------------- final projection: out = outn @ W^T + b ----------------
__global__ __launch_bounds__(256) void k_final(const float* __restrict__ outW, const float* __restrict__ outB,
                                               const char* __restrict__ ws, float* __restrict__ out){
  __shared__ float WT[DD*65];      // [d][e], padded
  __shared__ float s_x[4][DD];
  int tid = threadIdx.x, lane = tid & 63, wid = tid >> 6;
  for (int l = tid; l < EDIM*DD; l += 256){
    int e = l >> 9, d = l & 511;
    WT[d*65 + e] = outW[l];
  }
  __syncthreads();
  const float* outn = (const float*)(ws+OFF_OUTN);
  for (int it = 0; it < 16; it++){
    int p = blockIdx.x*64 + wid*16 + it;
    const float* x = outn + (size_t)p*DD;
    #pragma unroll
    for (int c = 0; c < 8; c++) s_x[wid][c*64 + lane] = x[c*64 + lane];
    __syncthreads();
    float acc = 0.f;
    for (int d = 0; d < DD; d++) acc = fmaf(s_x[wid][d], WT[d*65 + lane], acc);
    out[(size_t)p*EDIM + lane] = acc + outB[lane];
    __syncthreads();
  }
}

extern "C" void kernel_launch(void* const* d_in, const int* in_sizes, int n_in,
                              void* d_out, int out_size, void* d_ws, size_t ws_size,
                              hipStream_t stream) {
  const float* query = (const float*)d_in[0];
  const float* key   = (const float*)d_in[1];
  const float* value = (const float*)d_in[2];
  const float* projW = (const float*)d_in[3];
  const float* alpha = (const float*)d_in[4];
  const float* beta  = (const float*)d_in[5];
  const float* outW  = (const float*)d_in[6];
  const float* outB  = (const float*)d_in[7];
  char* ws = (char*)d_ws;
  float* out = (float*)d_out;

  k_init <<<1024, 256, 0, stream>>>(ws);
  k_sumsq<<<512,  256, 0, stream>>>(query, key, ws);
  k_hash <<<512,  256, 0, stream>>>(query, key, alpha, beta, ws);
  k_sort <<<128,  256, 0, stream>>>(ws);
  k_featq<<<2048, 256, 0, stream>>>(query, projW, ws);
  k_featk<<<2048, 256, 0, stream>>>(key, projW, ws);
  k_expk <<<16384,256, 0, stream>>>(ws);
  k_kv   <<<256,  256, 0, stream>>>(value, ws);
  k_ksum <<<32,   256, 0, stream>>>(ws);
  k_bucket<<<2048,256, 0, stream>>>(query, key, value, ws);
  k_combine<<<2048,256,0, stream>>>(ws);
  k_final<<<256,  256, 0, stream>>>(outW, outB, ws, out);
}

// Round 2
// 1480.027 us; speedup vs baseline: 1.5066x; 1.5066x over previous
//
#include <hip/hip_runtime.h>
#include <math.h>

// ---- problem constants ----
#define BH 32          // B*H
#define NSEQ 4096
#define EDIM 64
#define MDIM 128
#define NHASH 2
#define NBUCK 32
#define BSZC 128
#define BB 4
#define HH 8
#define DD 512

// ---- workspace layout (bytes) ----
static constexpr size_t OFF_SQQ  = 0;
static constexpr size_t SZ_ROWD  = (size_t)BH*NSEQ*8;
static constexpr size_t OFF_SQK  = OFF_SQQ + SZ_ROWD;
static constexpr size_t OFF_QH   = OFF_SQK + SZ_ROWD;
static constexpr size_t SZ_HASH  = (size_t)NHASH*BH*NSEQ*8;
static constexpr size_t OFF_KH   = OFF_QH + SZ_HASH;
static constexpr size_t OFF_MAXQ = OFF_KH + SZ_HASH;          // 32 doubles
static constexpr size_t OFF_MAXK = OFF_MAXQ + 256;
static constexpr size_t OFF_KLS  = OFF_MAXK + 256;            // 32 uint (ordered-float enc)
static constexpr size_t OFF_QPOS = OFF_KLS + 256;
static constexpr size_t SZ_POS   = (size_t)NHASH*BH*NSEQ*4;
static constexpr size_t OFF_KPOS = OFF_QPOS + SZ_POS;
static constexpr size_t OFF_QREV = OFF_KPOS + SZ_POS;
static constexpr size_t OFF_KREV = OFF_QREV + SZ_POS;
static constexpr size_t OFF_QP   = OFF_KREV + SZ_POS;         // bh*N*M f32
static constexpr size_t SZ_PRIME = (size_t)BH*NSEQ*MDIM*4;
static constexpr size_t OFF_KP   = OFF_QP + SZ_PRIME;
static constexpr size_t OFF_QLS  = OFF_KP + SZ_PRIME;         // bh*N f32
static constexpr size_t OFF_KV   = OFF_QLS + (size_t)BH*NSEQ*4;   // bh*M*E f32
static constexpr size_t OFF_KSUM = OFF_KV + (size_t)BH*MDIM*EDIM*4;
static constexpr size_t OFF_O    = OFF_KSUM + (size_t)BH*MDIM*4;  // NH*bh*N*E f32
static constexpr size_t OFF_LSE  = OFF_O + (size_t)NHASH*BH*NSEQ*EDIM*4;
static constexpr size_t OFF_DSUM = OFF_LSE + (size_t)NHASH*BH*NSEQ*4;
static constexpr size_t OFF_OUTN = OFF_DSUM + (size_t)NHASH*BH*NSEQ*4;  // B*N*D f32

#define SQRT_TEMP 0.3535533905932738f
#define HALF_LOG_M 2.4260151319598085f
#define LN2F 0.6931471805599453f

typedef __bf16 bf16_t;
typedef bf16_t bf16x8 __attribute__((ext_vector_type(8)));
typedef bf16_t bf16x4 __attribute__((ext_vector_type(4)));
typedef float  f32x16_t __attribute__((ext_vector_type(16)));
#define Z16 {0.f,0.f,0.f,0.f,0.f,0.f,0.f,0.f,0.f,0.f,0.f,0.f,0.f,0.f,0.f,0.f}

__device__ __forceinline__ unsigned encF(float f){
  unsigned u = __float_as_uint(f);
  return (u & 0x80000000u) ? ~u : (u | 0x80000000u);
}
__device__ __forceinline__ float decF(unsigned e){
  return __uint_as_float((e & 0x80000000u) ? (e ^ 0x80000000u) : ~e);
}

// ---------------- init ----------------
__global__ void k_init(char* __restrict__ ws){
  int idx = blockIdx.x*256 + threadIdx.x;
  if (idx < BH*MDIM*EDIM) ((float*)(ws+OFF_KV))[idx] = 0.0f;
  if (idx < BH){
    ((unsigned long long*)(ws+OFF_MAXQ))[idx] = 0ull;
    ((unsigned long long*)(ws+OFF_MAXK))[idx] = 0ull;
    ((unsigned*)(ws+OFF_KLS))[idx] = encF(-INFINITY);
  }
}

// ---------------- per-position squared norms + per-bh max ----------------
__global__ __launch_bounds__(256) void k_sumsq(const float* __restrict__ q, const float* __restrict__ k,
                                               char* __restrict__ ws){
  int p = blockIdx.x*256 + threadIdx.x;
  int bh = p >> 12, t = p & (NSEQ-1);
  int bo = bh >> 3, hh = bh & 7;
  const float* qr = q + ((size_t)bo*NSEQ + t)*DD + hh*EDIM;
  const float* kr = k + ((size_t)bo*NSEQ + t)*DD + hh*EDIM;
  double sq = 0.0, sk = 0.0;
  for (int e = 0; e < EDIM; e++){
    double a = qr[e]; sq = fma(a, a, sq);
    double b = kr[e]; sk = fma(b, b, sk);
  }
  ((double*)(ws+OFF_SQQ))[p] = sq;
  ((double*)(ws+OFF_SQK))[p] = sk;
  int lane = threadIdx.x & 63, wid = threadIdx.x >> 6;
  double mq = sq, mk = sk;
  for (int o = 32; o; o >>= 1){ mq = fmax(mq, __shfl_xor(mq, o)); mk = fmax(mk, __shfl_xor(mk, o)); }
  __shared__ double smq[4], smk[4];
  if (!lane){ smq[wid] = mq; smk[wid] = mk; }
  __syncthreads();
  if (!threadIdx.x){
    double a = fmax(fmax(smq[0], smq[1]), fmax(smq[2], smq[3]));
    double b = fmax(fmax(smk[0], smk[1]), fmax(smk[2], smk[3]));
    atomicMax((unsigned long long*)(ws+OFF_MAXQ) + bh, (unsigned long long)__double_as_longlong(a));
    atomicMax((unsigned long long*)(ws+OFF_MAXK) + bh, (unsigned long long)__double_as_longlong(b));
  }
}

// ---------------- E2LSH hashes in fp64 (ordering fidelity) ----------------
__global__ __launch_bounds__(256) void k_hash(const float* __restrict__ query, const float* __restrict__ key,
                                              const float* __restrict__ alpha, const float* __restrict__ beta,
                                              char* __restrict__ ws){
  int p = blockIdx.x*256 + threadIdx.x;
  int bh = p >> 12, t = p & (NSEQ-1);
  int bo = bh >> 3, hh = bh & 7;
  const float* qr = query + ((size_t)bo*NSEQ + t)*DD + hh*EDIM;
  const float* kr = key   + ((size_t)bo*NSEQ + t)*DD + hh*EDIM;
  double mqk = ((const double*)(ws+OFF_MAXQ))[bh] + ((const double*)(ws+OFF_MAXK))[bh];
  double sq  = ((const double*)(ws+OFF_SQQ))[p];
  double sk  = ((const double*)(ws+OFF_SQK))[p];
  double extq = sqrt(fmax(mqk - sq, 0.0));
  double extk = sqrt(fmax(mqk - sk, 0.0));
  double a0=0, a1=0, c0=0, c1=0;
  for (int e = 0; e < EDIM; e++){
    double qv = qr[e], kv = kr[e];
    double al0 = alpha[e*2+0], al1 = alpha[e*2+1];
    a0 = fma(qv, al0, a0); a1 = fma(qv, al1, a1);
    c0 = fma(kv, al0, c0); c1 = fma(kv, al1, c1);
  }
  a0 += extq * (double)alpha[64*2+0]; a1 += extq * (double)alpha[64*2+1];
  c0 += extk * (double)alpha[65*2+0]; c1 += extk * (double)alpha[65*2+1];
  double b0 = beta[0], b1 = beta[1];
  double* qh = (double*)(ws+OFF_QH);
  double* kh = (double*)(ws+OFF_KH);
  qh[p] = a0 + b0; qh[(size_t)BH*NSEQ + p] = a1 + b1;
  kh[p] = c0 + b0; kh[(size_t)BH*NSEQ + p] = c1 + b1;
}

// ---------------- bitonic argsort of 4096 per (hash, bh) row ----------------
// 512 threads: 8 compare-swaps per pass per thread (was 16) — pass latency halves.
__global__ __launch_bounds__(512) void k_sort(char* __restrict__ ws){
  int row = blockIdx.x;                 // 0..63 q rows, 64..127 k rows
  bool isK = row >= NHASH*BH;
  int r = isK ? row - NHASH*BH : row;
  const double* hash = (const double*)(ws + (isK ? OFF_KH : OFF_QH)) + (size_t)r*NSEQ;
  int* pos = (int*)(ws + (isK ? OFF_KPOS : OFF_QPOS)) + (size_t)r*NSEQ;
  int* rev = (int*)(ws + (isK ? OFF_KREV : OFF_QREV)) + (size_t)r*NSEQ;
  __shared__ double ks_[NSEQ];
  __shared__ int    is_[NSEQ];
  for (int i = threadIdx.x; i < NSEQ; i += 512){ ks_[i] = hash[i]; is_[i] = i; }
  __syncthreads();
  for (int k = 2; k <= NSEQ; k <<= 1){
    for (int j = k >> 1; j > 0; j >>= 1){
      for (int i = threadIdx.x; i < NSEQ; i += 512){
        int ixj = i ^ j;
        if (ixj > i){
          double a = ks_[i], b = ks_[ixj];
          bool up = ((i & k) == 0);
          if ((a > b) == up){
            ks_[i] = b; ks_[ixj] = a;
            int tmp = is_[i]; is_[i] = is_[ixj]; is_[ixj] = tmp;
          }
        }
      }
      __syncthreads();
    }
  }
  for (int i = threadIdx.x; i < NSEQ; i += 512){ int t = is_[i]; pos[i] = t; rev[t] = i; }
}

// ---------------- Performer features: query (per-position stab, fused exp) ----------------
__global__ __launch_bounds__(256) void k_featq(const float* __restrict__ query, const float* __restrict__ projW,
                                               char* __restrict__ ws){
  __shared__ float WT[EDIM*MDIM];     // WT[e*128+m] = W[m][e]
  __shared__ float s_q[4][EDIM];
  int tid = threadIdx.x, lane = tid & 63, wid = tid >> 6;
  for (int l = tid; l < EDIM*MDIM; l += 256) WT[l] = projW[(l & 127)*EDIM + (l >> 7)];
  __syncthreads();
  float* qp  = (float*)(ws+OFF_QP);
  float* qls = (float*)(ws+OFF_QLS);
  for (int it = 0; it < 16; it++){
    int p = blockIdx.x*64 + wid*16 + it;
    int bh = p >> 12, t = p & (NSEQ-1), bo = bh >> 3, hh = bh & 7;
    float xv = query[((size_t)bo*NSEQ + t)*DD + hh*EDIM + lane] * SQRT_TEMP;
    s_q[wid][lane] = xv;
    float ss = xv*xv;
    for (int o = 32; o; o >>= 1) ss += __shfl_xor(ss, o);
    __syncthreads();
    float a0 = 0.f, a1 = 0.f;
    for (int e = 0; e < EDIM; e++){
      float qe = s_q[wid][e];
      a0 = fmaf(qe, WT[e*128 + lane], a0);
      a1 = fmaf(qe, WT[e*128 + 64 + lane], a1);
    }
    float c = 0.5f*ss + HALF_LOG_M;
    float lp0 = a0 - c, lp1 = a1 - c;
    float mx = fmaxf(lp0, lp1);
    for (int o = 32; o; o >>= 1) mx = fmaxf(mx, __shfl_xor(mx, o));
    size_t base = (size_t)p*MDIM;
    qp[base + lane]      = expf(lp0 - mx);
    qp[base + 64 + lane] = expf(lp1 - mx);
    if (!lane) qls[p] = mx;
    __syncthreads();
  }
}

// ---------------- Performer features: key (raw log_phi + global max) ----------------
__global__ __launch_bounds__(256) void k_featk(const float* __restrict__ key, const float* __restrict__ projW,
                                               char* __restrict__ ws){
  __shared__ float WT[EDIM*MDIM];
  __shared__ float s_q[4][EDIM];
  int tid = threadIdx.x, lane = tid & 63, wid = tid >> 6;
  for (int l = tid; l < EDIM*MDIM; l += 256) WT[l] = projW[(l & 127)*EDIM + (l >> 7)];
  __syncthreads();
  float* kp = (float*)(ws+OFF_KP);
  int bh0 = (blockIdx.x*64) >> 12;
  float bmax = -INFINITY;
  for (int it = 0; it < 16; it++){
    int p = blockIdx.x*64 + wid*16 + it;
    int bh = p >> 12, t = p & (NSEQ-1), bo = bh >> 3, hh = bh & 7;
    float xv = key[((size_t)bo*NSEQ + t)*DD + hh*EDIM + lane] * SQRT_TEMP;
    s_q[wid][lane] = xv;
    float ss = xv*xv;
    for (int o = 32; o; o >>= 1) ss += __shfl_xor(ss, o);
    __syncthreads();
    float a0 = 0.f, a1 = 0.f;
    for (int e = 0; e < EDIM; e++){
      float qe = s_q[wid][e];
      a0 = fmaf(qe, WT[e*128 + lane], a0);
      a1 = fmaf(qe, WT[e*128 + 64 + lane], a1);
    }
    float c = 0.5f*ss + HALF_LOG_M;
    float lp0 = a0 - c, lp1 = a1 - c;
    size_t base = (size_t)p*MDIM;
    kp[base + lane]      = lp0;
    kp[base + 64 + lane] = lp1;
    float mx = fmaxf(lp0, lp1);
    for (int o = 32; o; o >>= 1) mx = fmaxf(mx, __shfl_xor(mx, o));
    bmax = fmaxf(bmax, mx);
    __syncthreads();
  }
  __shared__ float wm[4];
  if (!lane) wm[wid] = bmax;
  __syncthreads();
  if (!tid){
    float m = fmaxf(fmaxf(wm[0], wm[1]), fmaxf(wm[2], wm[3]));
    atomicMax((unsigned*)(ws+OFF_KLS) + bh0, encF(m));
  }
}

// ---------------- k_prime = exp(log_phi - stab) ----------------
__global__ void k_expk(char* __restrict__ ws){
  size_t idx = (size_t)blockIdx.x*256 + threadIdx.x;       // over bh*N*M/4
  float4* kp = (float4*)(ws+OFF_KP);
  int b = (int)(idx >> 17);                                // N*M/4 = 2^17 per bh
  float stab = decF(((const unsigned*)(ws+OFF_KLS))[b]);
  float4 v = kp[idx];
  v.x = expf(v.x - stab); v.y = expf(v.y - stab);
  v.z = expf(v.z - stab); v.w = expf(v.w - stab);
  kp[idx] = v;
}

// ---------------- kv[b][m][d] = sum_s kprime[s][m] * v[s][d] ----------------
__global__ __launch_bounds__(256) void k_kv(const float* __restrict__ value, char* __restrict__ ws){
  int b = blockIdx.x >> 3;
  int chunk = blockIdx.x & 7;
  int bo = b >> 3, hh = b & 7;
  const float* kp = (const float*)(ws+OFF_KP) + (size_t)b*NSEQ*MDIM;
  __shared__ float skp[16*MDIM];
  __shared__ float sv[16*EDIM];
  int d = threadIdx.x & 63, mg = threadIdx.x >> 6;  // mg == wave id
  float acc[32];
  #pragma unroll
  for (int i = 0; i < 32; i++) acc[i] = 0.f;
  for (int s0 = chunk*512; s0 < chunk*512 + 512; s0 += 16){
    __syncthreads();
    for (int l = threadIdx.x; l < 16*MDIM; l += 256)
      skp[l] = kp[(size_t)(s0 + (l >> 7))*MDIM + (l & 127)];
    for (int l = threadIdx.x; l < 16*EDIM; l += 256)
      sv[l] = value[((size_t)bo*NSEQ + s0 + (l >> 6))*DD + hh*EDIM + (l & 63)];
    __syncthreads();
    for (int ss = 0; ss < 16; ss++){
      float vv = sv[ss*64 + d];
      #pragma unroll
      for (int mi = 0; mi < 32; mi++)
        acc[mi] = fmaf(skp[ss*128 + mg*32 + mi], vv, acc[mi]);
    }
  }
  float* kv = (float*)(ws+OFF_KV) + (size_t)b*MDIM*EDIM;
  #pragma unroll
  for (int mi = 0; mi < 32; mi++) atomicAdd(&kv[(mg*32 + mi)*64 + d], acc[mi]);
}

// ---------------- ksum[b][m] = sum_s kprime[s][m] ----------------
__global__ __launch_bounds__(256) void k_ksum(char* __restrict__ ws){
  int b = blockIdx.x;
  int m = threadIdx.x & 127, sg = threadIdx.x >> 7;
  const float* kp = (const float*)(ws+OFF_KP) + (size_t)b*NSEQ*MDIM;
  float acc = 0.f;
  for (int s = sg; s < NSEQ; s += 2) acc += kp[(size_t)s*MDIM + m];
  __shared__ float red[256];
  red[threadIdx.x] = acc;
  __syncthreads();
  if (!sg) ((float*)(ws+OFF_KSUM))[b*MDIM + m] = red[m] + red[128 + m];
}

// ---------------- bucketed exact correction — MFMA version ----------------
// One block per (hash, bh, bucket). 4 waves; wave `wid` owns rows [wid*32, wid*32+32).
// Matmuls on v_mfma_f32_32x32x16_bf16:
//   A-frag: A[m=lane&31][k=(lane>>5)*8 + j]  (k-contiguous 8 elems → 16B loads)
//   B-frag: B[k=(lane>>5)*8 + j][n=lane&31]
//   C/D:    col=lane&31, row=(reg&3)+8*(reg>>2)+4*(lane>>5)   [measured m74/m101]
// Q / QP A-frags gather straight from global (read-once data — no LDS needed).
// K / KP / V staged in LDS bf16 with 16B-aligned padded strides; dots reuses the
// KP buffer (LDS round-trip C-layout -> A-layout). 73 KB LDS -> 2 blocks/CU.
__global__ __launch_bounds__(256, 2) void k_bucket(const float* __restrict__ query,
                                                   const float* __restrict__ key,
                                                   const float* __restrict__ value,
                                                   char* __restrict__ ws){
  // strides chosen 16B-aligned; b128 frag reads land 4-way max (~b128 floor)
  __shared__ __align__(16) bf16_t s_kT[128*72];    // Kt[j][e],  stride 72  (18.4 KB)
  __shared__ __align__(16) bf16_t s_kp[128*136];   // KPt[j][m], stride 136 (34.8 KB) — reused as dots[i][j]
  __shared__ __align__(16) bf16_t s_v [64*136];    // Vt[d][j],  stride 136 (17.4 KB)
  __shared__ int   s_tq[128], s_tk[128], s_qb[128], s_kb[128];
  __shared__ float s_pls[128];

  int blk = blockIdx.x;
  int h = blk >> 10;           // hash
  int b = (blk >> 5) & 31;     // bh
  int n = blk & 31;            // bucket
  int tid = threadIdx.x, lane = tid & 63, wid = tid >> 6;
  int col = lane & 31, half = lane >> 5;
  int bo = b >> 3, hh = b & 7;

  const int* kpos  = (const int*)(ws+OFF_KPOS) + ((size_t)h*BH + b)*NSEQ + n*BSZC;
  const int* qpos  = (const int*)(ws+OFF_QPOS) + ((size_t)h*BH + b)*NSEQ + n*BSZC;
  const int* qrev0 = (const int*)(ws+OFF_QREV) + (size_t)b*NSEQ;
  const int* qrev1 = (const int*)(ws+OFF_QREV) + ((size_t)BH + b)*NSEQ;
  const int* krev0 = (const int*)(ws+OFF_KREV) + (size_t)b*NSEQ;
  const int* krev1 = (const int*)(ws+OFF_KREV) + ((size_t)BH + b)*NSEQ;
  const float* qp_g = (const float*)(ws+OFF_QP) + (size_t)b*NSEQ*MDIM;
  const float* kp_g = (const float*)(ws+OFF_KP) + (size_t)b*NSEQ*MDIM;
  const float* qls  = (const float*)(ws+OFF_QLS) + (size_t)b*NSEQ;
  float klsb = decF(((const unsigned*)(ws+OFF_KLS))[b]);

  // -- per-row / per-col metadata --
  if (tid < 128){
    int t = qpos[tid];
    s_tq[tid]  = t;
    s_pls[tid] = qls[t] + klsb;
    s_qb[tid]  = (qrev0[t] >> 7) | ((qrev1[t] >> 7) << 16);
  } else {
    int j = tid - 128;
    int t = kpos[j];
    s_tk[j] = t;
    s_kb[j] = (krev0[t] >> 7) | ((krev1[t] >> 7) << 16);
  }
  __syncthreads();

  // -- stage B operands (fp32 global -> bf16 LDS) --
  for (int l = tid; l < 128*16; l += 256){            // K: 128 rows x 64 e, float4 granules
    int j = l >> 4, e4 = (l & 15) << 2;
    int t = s_tk[j];
    float4 x = *(const float4*)(key + ((size_t)bo*NSEQ + t)*DD + hh*EDIM + e4);
    bf16x4 y = {(bf16_t)x.x, (bf16_t)x.y, (bf16_t)x.z, (bf16_t)x.w};
    *(bf16x4*)&s_kT[j*72 + e4] = y;
  }
  for (int l = tid; l < 128*32; l += 256){            // KP: 128 rows x 128 m
    int j = l >> 5, m4 = (l & 31) << 2;
    int t = s_tk[j];
    float4 x = *(const float4*)(kp_g + (size_t)t*MDIM + m4);
    bf16x4 y = {(bf16_t)x.x, (bf16_t)x.y, (bf16_t)x.z, (bf16_t)x.w};
    *(bf16x4*)&s_kp[j*136 + m4] = y;
  }
  for (int l = tid; l < 128*64; l += 256){            // V transposed: Vt[d][j]
    int j = l >> 6, d = l & 63;
    int t = s_tk[j];
    s_v[d*136 + j] = (bf16_t)value[((size_t)bo*NSEQ + t)*DD + hh*EDIM + d];
  }
  __syncthreads();

  float* o_g   = (float*)(ws+OFF_O)    + ((size_t)h*BH + b)*NSEQ*EDIM;
  float* lse_g = (float*)(ws+OFF_LSE)  + ((size_t)h*BH + b)*NSEQ;
  float* dsm_g = (float*)(ws+OFF_DSUM) + ((size_t)h*BH + b)*NSEQ;

  int mrow = wid*32 + col;
  int tq_m = s_tq[mrow];

  // ---- matmul 1: inner = Q @ K^T  (K-dim 64, 16 mfma/wave) ----
  const float* qr = query + ((size_t)bo*NSEQ + tq_m)*DD + hh*EDIM + half*8;
  bf16x8 aq[4];
  #pragma unroll
  for (int kb = 0; kb < 4; kb++){
    float4 x0 = *(const float4*)(qr + kb*16);
    float4 x1 = *(const float4*)(qr + kb*16 + 4);
    bf16x8 a = {(bf16_t)x0.x,(bf16_t)x0.y,(bf16_t)x0.z,(bf16_t)x0.w,
                (bf16_t)x1.x,(bf16_t)x1.y,(bf16_t)x1.z,(bf16_t)x1.w};
    aq[kb] = a;
  }
  f32x16_t ain[4] = {Z16, Z16, Z16, Z16};
  #pragma unroll
  for (int jt = 0; jt < 4; jt++){
    #pragma unroll
    for (int kb = 0; kb < 4; kb++){
      bf16x8 bk = *(const bf16x8*)&s_kT[(jt*32 + col)*72 + kb*16 + half*8];
      ain[jt] = __builtin_amdgcn_mfma_f32_32x32x16_bf16(aq[kb], bk, ain[jt], 0, 0, 0);
    }
  }

  // ---- matmul 2: dots_prime = QP @ KP^T  (K-dim 128, 32 mfma/wave) ----
  const float* qpr = qp_g + (size_t)tq_m*MDIM + half*8;
  bf16x8 aqp[8];
  #pragma unroll
  for (int kb = 0; kb < 8; kb++){
    float4 x0 = *(const float4*)(qpr + kb*16);
    float4 x1 = *(const float4*)(qpr + kb*16 + 4);
    bf16x8 a = {(bf16_t)x0.x,(bf16_t)x0.y,(bf16_t)x0.z,(bf16_t)x0.w,
                (bf16_t)x1.x,(bf16_t)x1.y,(bf16_t)x1.z,(bf16_t)x1.w};
    aqp[kb] = a;
  }
  f32x16_t apr[4] = {Z16, Z16, Z16, Z16};
  #pragma unroll
  for (int jt = 0; jt < 4; jt++){
    #pragma unroll
    for (int kb = 0; kb < 8; kb++){
      bf16x8 bk = *(const bf16x8*)&s_kp[(jt*32 + col)*136 + kb*16 + half*8];
      apr[jt] = __builtin_amdgcn_mfma_f32_32x32x16_bf16(aqp[kb], bk, apr[jt], 0, 0, 0);
    }
  }
  __syncthreads();   // everyone done reading s_kp — safe to overwrite with dots

  // ---- softmax-correction (C layout: 16 rows per lane, 32 cols via lane&31) ----
  float pls_r[16]; int qb_r[16];
  #pragma unroll
  for (int i = 0; i < 16; i++){
    int r = wid*32 + (i & 3) + 8*(i >> 2) + 4*half;
    pls_r[i] = s_pls[r];
    qb_r[i]  = s_qb[r];
  }
  float mx[16];
  #pragma unroll
  for (int i = 0; i < 16; i++) mx[i] = -INFINITY;
  #pragma unroll
  for (int jt = 0; jt < 4; jt++){
    int kbp = s_kb[jt*32 + col];
    int kb0 = kbp & 0xffff, kb1 = kbp >> 16;
    #pragma unroll
    for (int i = 0; i < 16; i++){
      int dup2 = ((qb_r[i] & 0xffff) == kb0) & ((qb_r[i] >> 16) == kb1);
      float in = ain[jt][i]*0.125f - (dup2 ? LN2F : 0.0f);
      float dp = dup2 ? apr[jt][i]*0.5f : apr[jt][i];
      ain[jt][i] = in; apr[jt][i] = dp;
      mx[i] = fmaxf(mx[i], in);
    }
  }
  #pragma unroll
  for (int i = 0; i < 16; i++){
    #pragma unroll
    for (int o = 16; o; o >>= 1) mx[i] = fmaxf(mx[i], __shfl_xor(mx[i], o));
  }
  float L[16], eps[16], dsum[16];
  #pragma unroll
  for (int i = 0; i < 16; i++){
    L[i] = fmaxf(mx[i], pls_r[i]);
    eps[i] = expf(pls_r[i] - L[i]);
    dsum[i] = 0.f;
  }
  #pragma unroll
  for (int jt = 0; jt < 4; jt++){
    #pragma unroll
    for (int i = 0; i < 16; i++){
      float d = expf(ain[jt][i] - L[i]) - apr[jt][i]*eps[i];
      dsum[i] += d;
      int r = wid*32 + (i & 3) + 8*(i >> 2) + 4*half;
      s_kp[r*136 + jt*32 + col] = (bf16_t)d;        // dots[i][j] (A-layout for matmul 3)
    }
  }
  #pragma unroll
  for (int i = 0; i < 16; i++){
    #pragma unroll
    for (int o = 16; o; o >>= 1) dsum[i] += __shfl_xor(dsum[i], o);
  }
  __syncthreads();

  // ---- matmul 3: so = dots @ V  (K-dim 128, 16 mfma/wave) ----
  f32x16_t ao[2] = {Z16, Z16};
  #pragma unroll
  for (int kb = 0; kb < 8; kb++){
    bf16x8 ad = *(const bf16x8*)&s_kp[mrow*136 + kb*16 + half*8];
    #pragma unroll
    for (int dt = 0; dt < 2; dt++){
      bf16x8 bv = *(const bf16x8*)&s_v[(dt*32 + col)*136 + kb*16 + half*8];
      ao[dt] = __builtin_amdgcn_mfma_f32_32x32x16_bf16(ad, bv, ao[dt], 0, 0, 0);
    }
  }

  // ---- epilogue: scatter to unsorted positions ----
  #pragma unroll
  for (int i = 0; i < 16; i++){
    int r = wid*32 + (i & 3) + 8*(i >> 2) + 4*half;
    int t = s_tq[r];
    o_g[(size_t)t*EDIM + col]      = ao[0][i];
    o_g[(size_t)t*EDIM + 32 + col] = ao[1][i];
    if (col == 0){ lse_g[t] = L[i]; dsm_g[t] = dsum[i]; }
  }
}

// ---------------- combine (logsumexp over hashes + Performer branch) ----------------
__global__ __launch_bounds__(256) void k_combine(char* __restrict__ ws){
  int b = blockIdx.x >> 6;
  int chunk = blockIdx.x & 63;
  int tid = threadIdx.x, lane = tid & 63, wid = tid >> 6;
  __shared__ float s_kv[MDIM*EDIM];
  __shared__ float s_ks[MDIM];
  __shared__ float s_qp[4][MDIM];
  const float* kv = (const float*)(ws+OFF_KV) + (size_t)b*MDIM*EDIM;
  for (int l = tid; l < MDIM*EDIM; l += 256) s_kv[l] = kv[l];
  if (tid < MDIM) s_ks[tid] = ((const float*)(ws+OFF_KSUM))[b*MDIM + tid];
  __syncthreads();
  const float* qp_g  = (const float*)(ws+OFF_QP) + (size_t)b*NSEQ*MDIM;
  const float* qls   = (const float*)(ws+OFF_QLS) + (size_t)b*NSEQ;
  const float* lse_g = (const float*)(ws+OFF_LSE);
  const float* dsm_g = (const float*)(ws+OFF_DSUM);
  const float* o_g   = (const float*)(ws+OFF_O);
  float* outn = (float*)(ws+OFF_OUTN);
  float klsb = decF(((const unsigned*)(ws+OFF_KLS))[b]);
  int bo = b >> 3, hh = b & 7;
  for (int it = 0; it < 16; it++){
    int t = chunk*64 + wid*16 + it;
    float qp0 = qp_g[(size_t)t*MDIM + lane];
    float qp1 = qp_g[(size_t)t*MDIM + 64 + lane];
    s_qp[wid][lane] = qp0; s_qp[wid][64 + lane] = qp1;
    __syncthreads();
    float qkv = 0.f;
    for (int m = 0; m < 128; m++) qkv = fmaf(s_qp[wid][m], s_kv[m*64 + lane], qkv);
    float qk1 = qp0*s_ks[lane] + qp1*s_ks[64 + lane];
    for (int o = 32; o; o >>= 1) qk1 += __shfl_xor(qk1, o);
    size_t pidx = (size_t)b*NSEQ + t;
    float l0 = lse_g[pidx], l1 = lse_g[(size_t)BH*NSEQ + pidx];
    float mx = fmaxf(l0, l1);
    float nls = mx + logf(expf(l0 - mx) + expf(l1 - mx));
    float p0 = expf(l0 - nls), p1 = expf(l1 - nls);
    float ps = expf(qls[t] + klsb - nls);
    float o0 = o_g[pidx*EDIM + lane];
    float o1 = o_g[((size_t)BH*NSEQ + pidx)*EDIM + lane];
    float ds0 = dsm_g[pidx], ds1 = dsm_g[(size_t)BH*NSEQ + pidx];
    float outv = o0*p0 + o1*p1 + qkv*ps;
    float nrm  = ds0*p0 + ds1*p1 + qk1*ps;
    outn[((size_t)bo*NSEQ + t)*DD + hh*EDIM + lane] = outv / fmaxf(nrm, 1e-6f);
    __syncthreads();
  }
}

// ---------------- final projection: out = outn @ W^T + b ----------------
__global__ __launch_bounds__(256) void k_final(const float* __restrict__ outW, const float* __restrict__ outB,
                                               const char* __restrict__ ws, float* __restrict__ out){
  __shared__ float WT[DD*65];      // [d][e], padded
  __shared__ float s_x[4][DD];
  int tid = threadIdx.x, lane = tid & 63, wid = tid >> 6;
  for (int l = tid; l < EDIM*DD; l += 256){
    int e = l >> 9, d = l & 511;
    WT[d*65 + e] = outW[l];
  }
  __syncthreads();
  const float* outn = (const float*)(ws+OFF_OUTN);
  for (int it = 0; it < 16; it++){
    int p = blockIdx.x*64 + wid*16 + it;
    const float* x = outn + (size_t)p*DD;
    #pragma unroll
    for (int c = 0; c < 8; c++) s_x[wid][c*64 + lane] = x[c*64 + lane];
    __syncthreads();
    float acc = 0.f;
    for (int d = 0; d < DD; d++) acc = fmaf(s_x[wid][d], WT[d*65 + lane], acc);
    out[(size_t)p*EDIM + lane] = acc + outB[lane];
    __syncthreads();
  }
}

extern "C" void kernel_launch(void* const* d_in, const int* in_sizes, int n_in,
                              void* d_out, int out_size, void* d_ws, size_t ws_size,
                              hipStream_t stream) {
  const float* query = (const float*)d_in[0];
  const float* key   = (const float*)d_in[1];
  const float* value = (const float*)d_in[2];
  const float* projW = (const float*)d_in[3];
  const float* alpha = (const float*)d_in[4];
  const float* beta  = (const float*)d_in[5];
  const float* outW  = (const float*)d_in[6];
  const float* outB  = (const float*)d_in[7];
  char* ws = (char*)d_ws;
  float* out = (float*)d_out;

  k_init <<<1024, 256, 0, stream>>>(ws);
  k_sumsq<<<512,  256, 0, stream>>>(query, key, ws);
  k_hash <<<512,  256, 0, stream>>>(query, key, alpha, beta, ws);
  k_sort <<<128,  512, 0, stream>>>(ws);
  k_featq<<<2048, 256, 0, stream>>>(query, projW, ws);
  k_featk<<<2048, 256, 0, stream>>>(key, projW, ws);
  k_expk <<<16384,256, 0, stream>>>(ws);
  k_kv   <<<256,  256, 0, stream>>>(value, ws);
  k_ksum <<<32,   256, 0, stream>>>(ws);
  k_bucket<<<2048,256, 0, stream>>>(query, key, value, ws);
  k_combine<<<2048,256,0, stream>>>(ws);
  k_final<<<256,  256, 0, stream>>>(outW, outB, ws, out);
}

// Round 3
// 1153.397 us; speedup vs baseline: 1.9332x; 1.2832x over previous
//
#include <hip/hip_runtime.h>
#include <math.h>

// ---- problem constants ----
#define BH 32          // B*H
#define NSEQ 4096
#define EDIM 64
#define MDIM 128
#define NHASH 2
#define NBUCK 32
#define BSZC 128
#define BB 4
#define HH 8
#define DD 512

// ---- workspace layout (bytes) ----
static constexpr size_t OFF_SQQ  = 0;
static constexpr size_t SZ_ROWD  = (size_t)BH*NSEQ*8;
static constexpr size_t OFF_SQK  = OFF_SQQ + SZ_ROWD;
static constexpr size_t OFF_QH   = OFF_SQK + SZ_ROWD;
static constexpr size_t SZ_HASH  = (size_t)NHASH*BH*NSEQ*8;
static constexpr size_t OFF_KH   = OFF_QH + SZ_HASH;
static constexpr size_t OFF_MAXQ = OFF_KH + SZ_HASH;          // 32 doubles
static constexpr size_t OFF_MAXK = OFF_MAXQ + 256;
static constexpr size_t OFF_KLS  = OFF_MAXK + 256;            // 32 uint (ordered-float enc)
static constexpr size_t OFF_QPOS = OFF_KLS + 256;
static constexpr size_t SZ_POS   = (size_t)NHASH*BH*NSEQ*4;
static constexpr size_t OFF_KPOS = OFF_QPOS + SZ_POS;
static constexpr size_t OFF_QREV = OFF_KPOS + SZ_POS;
static constexpr size_t OFF_KREV = OFF_QREV + SZ_POS;
static constexpr size_t OFF_QP   = OFF_KREV + SZ_POS;         // bh*N*M f32
static constexpr size_t SZ_PRIME = (size_t)BH*NSEQ*MDIM*4;
static constexpr size_t OFF_KP   = OFF_QP + SZ_PRIME;
static constexpr size_t OFF_QLS  = OFF_KP + SZ_PRIME;         // bh*N f32
static constexpr size_t OFF_KV   = OFF_QLS + (size_t)BH*NSEQ*4;   // bh*M*E f32
static constexpr size_t OFF_KSUM = OFF_KV + (size_t)BH*MDIM*EDIM*4;
static constexpr size_t OFF_O    = OFF_KSUM + (size_t)BH*MDIM*4;  // NH*bh*N*E f32
static constexpr size_t OFF_LSE  = OFF_O + (size_t)NHASH*BH*NSEQ*EDIM*4;
static constexpr size_t OFF_DSUM = OFF_LSE + (size_t)NHASH*BH*NSEQ*4;
static constexpr size_t OFF_OUTN = OFF_DSUM + (size_t)NHASH*BH*NSEQ*4;  // B*N*D f32

#define SQRT_TEMP 0.3535533905932738f
#define HALF_LOG_M 2.4260151319598085f
#define LN2F 0.6931471805599453f

typedef __bf16 bf16_t;
typedef bf16_t bf16x8 __attribute__((ext_vector_type(8)));
typedef bf16_t bf16x4 __attribute__((ext_vector_type(4)));
typedef float  f32x16_t __attribute__((ext_vector_type(16)));
#define Z16 {0.f,0.f,0.f,0.f,0.f,0.f,0.f,0.f,0.f,0.f,0.f,0.f,0.f,0.f,0.f,0.f}

__device__ __forceinline__ unsigned encF(float f){
  unsigned u = __float_as_uint(f);
  return (u & 0x80000000u) ? ~u : (u | 0x80000000u);
}
__device__ __forceinline__ float decF(unsigned e){
  return __uint_as_float((e & 0x80000000u) ? (e ^ 0x80000000u) : ~e);
}

// ---------------- init ----------------
__global__ void k_init(char* __restrict__ ws){
  int idx = blockIdx.x*256 + threadIdx.x;
  if (idx < BH*MDIM*EDIM) ((float*)(ws+OFF_KV))[idx] = 0.0f;
  if (idx < BH*MDIM) ((float*)(ws+OFF_KSUM))[idx] = 0.0f;
  if (idx < BH){
    ((unsigned long long*)(ws+OFF_MAXQ))[idx] = 0ull;
    ((unsigned long long*)(ws+OFF_MAXK))[idx] = 0ull;
    ((unsigned*)(ws+OFF_KLS))[idx] = encF(-INFINITY);
  }
}

// ---------------- per-position squared norms + per-bh max ----------------
__global__ __launch_bounds__(256) void k_sumsq(const float* __restrict__ q, const float* __restrict__ k,
                                               char* __restrict__ ws){
  int p = blockIdx.x*256 + threadIdx.x;
  int bh = p >> 12, t = p & (NSEQ-1);
  int bo = bh >> 3, hh = bh & 7;
  const float* qr = q + ((size_t)bo*NSEQ + t)*DD + hh*EDIM;
  const float* kr = k + ((size_t)bo*NSEQ + t)*DD + hh*EDIM;
  double sq = 0.0, sk = 0.0;
  for (int e = 0; e < EDIM; e++){
    double a = qr[e]; sq = fma(a, a, sq);
    double b = kr[e]; sk = fma(b, b, sk);
  }
  ((double*)(ws+OFF_SQQ))[p] = sq;
  ((double*)(ws+OFF_SQK))[p] = sk;
  int lane = threadIdx.x & 63, wid = threadIdx.x >> 6;
  double mq = sq, mk = sk;
  for (int o = 32; o; o >>= 1){ mq = fmax(mq, __shfl_xor(mq, o)); mk = fmax(mk, __shfl_xor(mk, o)); }
  __shared__ double smq[4], smk[4];
  if (!lane){ smq[wid] = mq; smk[wid] = mk; }
  __syncthreads();
  if (!threadIdx.x){
    double a = fmax(fmax(smq[0], smq[1]), fmax(smq[2], smq[3]));
    double b = fmax(fmax(smk[0], smk[1]), fmax(smk[2], smk[3]));
    atomicMax((unsigned long long*)(ws+OFF_MAXQ) + bh, (unsigned long long)__double_as_longlong(a));
    atomicMax((unsigned long long*)(ws+OFF_MAXK) + bh, (unsigned long long)__double_as_longlong(b));
  }
}

// ---------------- E2LSH hashes in fp64 (ordering fidelity) ----------------
__global__ __launch_bounds__(256) void k_hash(const float* __restrict__ query, const float* __restrict__ key,
                                              const float* __restrict__ alpha, const float* __restrict__ beta,
                                              char* __restrict__ ws){
  int p = blockIdx.x*256 + threadIdx.x;
  int bh = p >> 12, t = p & (NSEQ-1);
  int bo = bh >> 3, hh = bh & 7;
  const float* qr = query + ((size_t)bo*NSEQ + t)*DD + hh*EDIM;
  const float* kr = key   + ((size_t)bo*NSEQ + t)*DD + hh*EDIM;
  double mqk = ((const double*)(ws+OFF_MAXQ))[bh] + ((const double*)(ws+OFF_MAXK))[bh];
  double sq  = ((const double*)(ws+OFF_SQQ))[p];
  double sk  = ((const double*)(ws+OFF_SQK))[p];
  double extq = sqrt(fmax(mqk - sq, 0.0));
  double extk = sqrt(fmax(mqk - sk, 0.0));
  double a0=0, a1=0, c0=0, c1=0;
  for (int e = 0; e < EDIM; e++){
    double qv = qr[e], kv = kr[e];
    double al0 = alpha[e*2+0], al1 = alpha[e*2+1];
    a0 = fma(qv, al0, a0); a1 = fma(qv, al1, a1);
    c0 = fma(kv, al0, c0); c1 = fma(kv, al1, c1);
  }
  a0 += extq * (double)alpha[64*2+0]; a1 += extq * (double)alpha[64*2+1];
  c0 += extk * (double)alpha[65*2+0]; c1 += extk * (double)alpha[65*2+1];
  double b0 = beta[0], b1 = beta[1];
  double* qh = (double*)(ws+OFF_QH);
  double* kh = (double*)(ws+OFF_KH);
  qh[p] = a0 + b0; qh[(size_t)BH*NSEQ + p] = a1 + b1;
  kh[p] = c0 + b0; kh[(size_t)BH*NSEQ + p] = c1 + b1;
}

// ---------------- bitonic argsort of 4096 per (hash, bh) row ----------------
__global__ __launch_bounds__(512) void k_sort(char* __restrict__ ws){
  int row = blockIdx.x;                 // 0..63 q rows, 64..127 k rows
  bool isK = row >= NHASH*BH;
  int r = isK ? row - NHASH*BH : row;
  const double* hash = (const double*)(ws + (isK ? OFF_KH : OFF_QH)) + (size_t)r*NSEQ;
  int* pos = (int*)(ws + (isK ? OFF_KPOS : OFF_QPOS)) + (size_t)r*NSEQ;
  int* rev = (int*)(ws + (isK ? OFF_KREV : OFF_QREV)) + (size_t)r*NSEQ;
  __shared__ double ks_[NSEQ];
  __shared__ int    is_[NSEQ];
  for (int i = threadIdx.x; i < NSEQ; i += 512){ ks_[i] = hash[i]; is_[i] = i; }
  __syncthreads();
  for (int k = 2; k <= NSEQ; k <<= 1){
    for (int j = k >> 1; j > 0; j >>= 1){
      for (int i = threadIdx.x; i < NSEQ; i += 512){
        int ixj = i ^ j;
        if (ixj > i){
          double a = ks_[i], b = ks_[ixj];
          bool up = ((i & k) == 0);
          if ((a > b) == up){
            ks_[i] = b; ks_[ixj] = a;
            int tmp = is_[i]; is_[i] = is_[ixj]; is_[ixj] = tmp;
          }
        }
      }
      __syncthreads();
    }
  }
  for (int i = threadIdx.x; i < NSEQ; i += 512){ int t = is_[i]; pos[i] = t; rev[t] = i; }
}

// ---------------- Performer features: query (per-position stab, fused exp) ----------------
__global__ __launch_bounds__(256) void k_featq(const float* __restrict__ query, const float* __restrict__ projW,
                                               char* __restrict__ ws){
  __shared__ float WT[EDIM*MDIM];     // WT[e*128+m] = W[m][e]
  __shared__ float s_q[4][EDIM];
  int tid = threadIdx.x, lane = tid & 63, wid = tid >> 6;
  for (int l = tid; l < EDIM*MDIM; l += 256) WT[l] = projW[(l & 127)*EDIM + (l >> 7)];
  __syncthreads();
  float* qp  = (float*)(ws+OFF_QP);
  float* qls = (float*)(ws+OFF_QLS);
  for (int it = 0; it < 16; it++){
    int p = blockIdx.x*64 + wid*16 + it;
    int bh = p >> 12, t = p & (NSEQ-1), bo = bh >> 3, hh = bh & 7;
    float xv = query[((size_t)bo*NSEQ + t)*DD + hh*EDIM + lane] * SQRT_TEMP;
    s_q[wid][lane] = xv;
    float ss = xv*xv;
    for (int o = 32; o; o >>= 1) ss += __shfl_xor(ss, o);
    __syncthreads();
    float a0 = 0.f, a1 = 0.f;
    for (int e = 0; e < EDIM; e++){
      float qe = s_q[wid][e];
      a0 = fmaf(qe, WT[e*128 + lane], a0);
      a1 = fmaf(qe, WT[e*128 + 64 + lane], a1);
    }
    float c = 0.5f*ss + HALF_LOG_M;
    float lp0 = a0 - c, lp1 = a1 - c;
    float mx = fmaxf(lp0, lp1);
    for (int o = 32; o; o >>= 1) mx = fmaxf(mx, __shfl_xor(mx, o));
    size_t base = (size_t)p*MDIM;
    qp[base + lane]      = expf(lp0 - mx);
    qp[base + 64 + lane] = expf(lp1 - mx);
    if (!lane) qls[p] = mx;
    __syncthreads();
  }
}

// ---------------- Performer features: key (raw log_phi + global max) ----------------
__global__ __launch_bounds__(256) void k_featk(const float* __restrict__ key, const float* __restrict__ projW,
                                               char* __restrict__ ws){
  __shared__ float WT[EDIM*MDIM];
  __shared__ float s_q[4][EDIM];
  int tid = threadIdx.x, lane = tid & 63, wid = tid >> 6;
  for (int l = tid; l < EDIM*MDIM; l += 256) WT[l] = projW[(l & 127)*EDIM + (l >> 7)];
  __syncthreads();
  float* kp = (float*)(ws+OFF_KP);
  int bh0 = (blockIdx.x*64) >> 12;
  float bmax = -INFINITY;
  for (int it = 0; it < 16; it++){
    int p = blockIdx.x*64 + wid*16 + it;
    int bh = p >> 12, t = p & (NSEQ-1), bo = bh >> 3, hh = bh & 7;
    float xv = key[((size_t)bo*NSEQ + t)*DD + hh*EDIM + lane] * SQRT_TEMP;
    s_q[wid][lane] = xv;
    float ss = xv*xv;
    for (int o = 32; o; o >>= 1) ss += __shfl_xor(ss, o);
    __syncthreads();
    float a0 = 0.f, a1 = 0.f;
    for (int e = 0; e < EDIM; e++){
      float qe = s_q[wid][e];
      a0 = fmaf(qe, WT[e*128 + lane], a0);
      a1 = fmaf(qe, WT[e*128 + 64 + lane], a1);
    }
    float c = 0.5f*ss + HALF_LOG_M;
    float lp0 = a0 - c, lp1 = a1 - c;
    size_t base = (size_t)p*MDIM;
    kp[base + lane]      = lp0;
    kp[base + 64 + lane] = lp1;
    float mx = fmaxf(lp0, lp1);
    for (int o = 32; o; o >>= 1) mx = fmaxf(mx, __shfl_xor(mx, o));
    bmax = fmaxf(bmax, mx);
    __syncthreads();
  }
  __shared__ float wm[4];
  if (!lane) wm[wid] = bmax;
  __syncthreads();
  if (!tid){
    float m = fmaxf(fmaxf(wm[0], wm[1]), fmaxf(wm[2], wm[3]));
    atomicMax((unsigned*)(ws+OFF_KLS) + bh0, encF(m));
  }
}

// ---------------- k_prime = exp(log_phi - stab) ----------------
__global__ void k_expk(char* __restrict__ ws){
  size_t idx = (size_t)blockIdx.x*256 + threadIdx.x;       // over bh*N*M/4
  float4* kp = (float4*)(ws+OFF_KP);
  int b = (int)(idx >> 17);                                // N*M/4 = 2^17 per bh
  float stab = decF(((const unsigned*)(ws+OFF_KLS))[b]);
  float4 v = kp[idx];
  v.x = expf(v.x - stab); v.y = expf(v.y - stab);
  v.z = expf(v.z - stab); v.w = expf(v.w - stab);
  kp[idx] = v;
}

// ---------------- kv[b][m][d] = sum_s kprime[s][m] * v[s][d]  (+ fused ksum) ----------------
__global__ __launch_bounds__(256) void k_kv(const float* __restrict__ value, char* __restrict__ ws){
  int b = blockIdx.x >> 3;
  int chunk = blockIdx.x & 7;
  int bo = b >> 3, hh = b & 7;
  const float* kp = (const float*)(ws+OFF_KP) + (size_t)b*NSEQ*MDIM;
  __shared__ float skp[16*MDIM];
  __shared__ float sv[16*EDIM];
  int d = threadIdx.x & 63, mg = threadIdx.x >> 6;  // mg == wave id
  float acc[32];
  #pragma unroll
  for (int i = 0; i < 32; i++) acc[i] = 0.f;
  float ksacc = 0.f;                                 // tid<128: column-sum of kprime
  for (int s0 = chunk*512; s0 < chunk*512 + 512; s0 += 16){
    __syncthreads();
    for (int l = threadIdx.x; l < 16*MDIM; l += 256)
      skp[l] = kp[(size_t)(s0 + (l >> 7))*MDIM + (l & 127)];
    for (int l = threadIdx.x; l < 16*EDIM; l += 256)
      sv[l] = value[((size_t)bo*NSEQ + s0 + (l >> 6))*DD + hh*EDIM + (l & 63)];
    __syncthreads();
    for (int ss = 0; ss < 16; ss++){
      float vv = sv[ss*64 + d];
      #pragma unroll
      for (int mi = 0; mi < 32; mi++)
        acc[mi] = fmaf(skp[ss*128 + mg*32 + mi], vv, acc[mi]);
    }
    if (threadIdx.x < 128){
      #pragma unroll
      for (int ss = 0; ss < 16; ss++) ksacc += skp[ss*128 + threadIdx.x];
    }
  }
  float* kv = (float*)(ws+OFF_KV) + (size_t)b*MDIM*EDIM;
  #pragma unroll
  for (int mi = 0; mi < 32; mi++) atomicAdd(&kv[(mg*32 + mi)*64 + d], acc[mi]);
  if (threadIdx.x < 128)
    atomicAdd((float*)(ws+OFF_KSUM) + b*MDIM + threadIdx.x, ksacc);
}

// ---------------- bucketed exact correction — MFMA version ----------------
// One block per (hash, bh, bucket). 4 waves; wave `wid` owns rows [wid*32, wid*32+32).
// Matmuls on v_mfma_f32_32x32x16_bf16:
//   A-frag: A[m=lane&31][k=(lane>>5)*8 + j]  (k-contiguous 8 elems -> 16B loads)
//   B-frag: B[k=(lane>>5)*8 + j][n=lane&31]
//   C/D:    col=lane&31, row=(reg&3)+8*(reg>>2)+4*(lane>>5)   [measured m74/m101]
__global__ __launch_bounds__(256, 2) void k_bucket(const float* __restrict__ query,
                                                   const float* __restrict__ key,
                                                   const float* __restrict__ value,
                                                   char* __restrict__ ws){
  __shared__ __align__(16) bf16_t s_kT[128*72];    // Kt[j][e],  stride 72  (18.4 KB)
  __shared__ __align__(16) bf16_t s_kp[128*136];   // KPt[j][m], stride 136 (34.8 KB) — reused as dots[i][j]
  __shared__ __align__(16) bf16_t s_v [64*136];    // Vt[d][j],  stride 136 (17.4 KB)
  __shared__ int   s_tq[128], s_tk[128], s_qb[128], s_kb[128];
  __shared__ float s_pls[128];

  int blk = blockIdx.x;
  int h = blk >> 10;           // hash
  int b = (blk >> 5) & 31;     // bh
  int n = blk & 31;            // bucket
  int tid = threadIdx.x, lane = tid & 63, wid = tid >> 6;
  int col = lane & 31, half = lane >> 5;
  int bo = b >> 3, hh = b & 7;

  const int* kpos  = (const int*)(ws+OFF_KPOS) + ((size_t)h*BH + b)*NSEQ + n*BSZC;
  const int* qpos  = (const int*)(ws+OFF_QPOS) + ((size_t)h*BH + b)*NSEQ + n*BSZC;
  const int* qrev0 = (const int*)(ws+OFF_QREV) + (size_t)b*NSEQ;
  const int* qrev1 = (const int*)(ws+OFF_QREV) + ((size_t)BH + b)*NSEQ;
  const int* krev0 = (const int*)(ws+OFF_KREV) + (size_t)b*NSEQ;
  const int* krev1 = (const int*)(ws+OFF_KREV) + ((size_t)BH + b)*NSEQ;
  const float* qp_g = (const float*)(ws+OFF_QP) + (size_t)b*NSEQ*MDIM;
  const float* kp_g = (const float*)(ws+OFF_KP) + (size_t)b*NSEQ*MDIM;
  const float* qls  = (const float*)(ws+OFF_QLS) + (size_t)b*NSEQ;
  float klsb = decF(((const unsigned*)(ws+OFF_KLS))[b]);

  // -- per-row / per-col metadata --
  if (tid < 128){
    int t = qpos[tid];
    s_tq[tid]  = t;
    s_pls[tid] = qls[t] + klsb;
    s_qb[tid]  = (qrev0[t] >> 7) | ((qrev1[t] >> 7) << 16);
  } else {
    int j = tid - 128;
    int t = kpos[j];
    s_tk[j] = t;
    s_kb[j] = (krev0[t] >> 7) | ((krev1[t] >> 7) << 16);
  }
  __syncthreads();

  // -- stage B operands (fp32 global -> bf16 LDS) --
  for (int l = tid; l < 128*16; l += 256){            // K: 128 rows x 64 e
    int j = l >> 4, e4 = (l & 15) << 2;
    int t = s_tk[j];
    float4 x = *(const float4*)(key + ((size_t)bo*NSEQ + t)*DD + hh*EDIM + e4);
    bf16x4 y = {(bf16_t)x.x, (bf16_t)x.y, (bf16_t)x.z, (bf16_t)x.w};
    *(bf16x4*)&s_kT[j*72 + e4] = y;
  }
  for (int l = tid; l < 128*32; l += 256){            // KP: 128 rows x 128 m
    int j = l >> 5, m4 = (l & 31) << 2;
    int t = s_tk[j];
    float4 x = *(const float4*)(kp_g + (size_t)t*MDIM + m4);
    bf16x4 y = {(bf16_t)x.x, (bf16_t)x.y, (bf16_t)x.z, (bf16_t)x.w};
    *(bf16x4*)&s_kp[j*136 + m4] = y;
  }
  for (int l = tid; l < 128*64; l += 256){            // V transposed: Vt[d][j]
    int j = l >> 6, d = l & 63;
    int t = s_tk[j];
    s_v[d*136 + j] = (bf16_t)value[((size_t)bo*NSEQ + t)*DD + hh*EDIM + d];
  }
  __syncthreads();

  float* o_g   = (float*)(ws+OFF_O)    + ((size_t)h*BH + b)*NSEQ*EDIM;
  float* lse_g = (float*)(ws+OFF_LSE)  + ((size_t)h*BH + b)*NSEQ;
  float* dsm_g = (float*)(ws+OFF_DSUM) + ((size_t)h*BH + b)*NSEQ;

  int mrow = wid*32 + col;
  int tq_m = s_tq[mrow];

  // ---- matmul 1: inner = Q @ K^T ----
  const float* qr = query + ((size_t)bo*NSEQ + tq_m)*DD + hh*EDIM + half*8;
  bf16x8 aq[4];
  #pragma unroll
  for (int kb = 0; kb < 4; kb++){
    float4 x0 = *(const float4*)(qr + kb*16);
    float4 x1 = *(const float4*)(qr + kb*16 + 4);
    bf16x8 a = {(bf16_t)x0.x,(bf16_t)x0.y,(bf16_t)x0.z,(bf16_t)x0.w,
                (bf16_t)x1.x,(bf16_t)x1.y,(bf16_t)x1.z,(bf16_t)x1.w};
    aq[kb] = a;
  }
  f32x16_t ain[4] = {Z16, Z16, Z16, Z16};
  #pragma unroll
  for (int jt = 0; jt < 4; jt++){
    #pragma unroll
    for (int kb = 0; kb < 4; kb++){
      bf16x8 bk = *(const bf16x8*)&s_kT[(jt*32 + col)*72 + kb*16 + half*8];
      ain[jt] = __builtin_amdgcn_mfma_f32_32x32x16_bf16(aq[kb], bk, ain[jt], 0, 0, 0);
    }
  }

  // ---- matmul 2: dots_prime = QP @ KP^T ----
  const float* qpr = qp_g + (size_t)tq_m*MDIM + half*8;
  bf16x8 aqp[8];
  #pragma unroll
  for (int kb = 0; kb < 8; kb++){
    float4 x0 = *(const float4*)(qpr + kb*16);
    float4 x1 = *(const float4*)(qpr + kb*16 + 4);
    bf16x8 a = {(bf16_t)x0.x,(bf16_t)x0.y,(bf16_t)x0.z,(bf16_t)x0.w,
                (bf16_t)x1.x,(bf16_t)x1.y,(bf16_t)x1.z,(bf16_t)x1.w};
    aqp[kb] = a;
  }
  f32x16_t apr[4] = {Z16, Z16, Z16, Z16};
  #pragma unroll
  for (int jt = 0; jt < 4; jt++){
    #pragma unroll
    for (int kb = 0; kb < 8; kb++){
      bf16x8 bk = *(const bf16x8*)&s_kp[(jt*32 + col)*136 + kb*16 + half*8];
      apr[jt] = __builtin_amdgcn_mfma_f32_32x32x16_bf16(aqp[kb], bk, apr[jt], 0, 0, 0);
    }
  }
  __syncthreads();   // everyone done reading s_kp — safe to overwrite with dots

  // ---- softmax-correction ----
  float pls_r[16]; int qb_r[16];
  #pragma unroll
  for (int i = 0; i < 16; i++){
    int r = wid*32 + (i & 3) + 8*(i >> 2) + 4*half;
    pls_r[i] = s_pls[r];
    qb_r[i]  = s_qb[r];
  }
  float mx[16];
  #pragma unroll
  for (int i = 0; i < 16; i++) mx[i] = -INFINITY;
  #pragma unroll
  for (int jt = 0; jt < 4; jt++){
    int kbp = s_kb[jt*32 + col];
    int kb0 = kbp & 0xffff, kb1 = kbp >> 16;
    #pragma unroll
    for (int i = 0; i < 16; i++){
      int dup2 = ((qb_r[i] & 0xffff) == kb0) & ((qb_r[i] >> 16) == kb1);
      float in = ain[jt][i]*0.125f - (dup2 ? LN2F : 0.0f);
      float dp = dup2 ? apr[jt][i]*0.5f : apr[jt][i];
      ain[jt][i] = in; apr[jt][i] = dp;
      mx[i] = fmaxf(mx[i], in);
    }
  }
  #pragma unroll
  for (int i = 0; i < 16; i++){
    #pragma unroll
    for (int o = 16; o; o >>= 1) mx[i] = fmaxf(mx[i], __shfl_xor(mx[i], o));
  }
  float L[16], eps[16], dsum[16];
  #pragma unroll
  for (int i = 0; i < 16; i++){
    L[i] = fmaxf(mx[i], pls_r[i]);
    eps[i] = expf(pls_r[i] - L[i]);
    dsum[i] = 0.f;
  }
  #pragma unroll
  for (int jt = 0; jt < 4; jt++){
    #pragma unroll
    for (int i = 0; i < 16; i++){
      float d = expf(ain[jt][i] - L[i]) - apr[jt][i]*eps[i];
      dsum[i] += d;
      int r = wid*32 + (i & 3) + 8*(i >> 2) + 4*half;
      s_kp[r*136 + jt*32 + col] = (bf16_t)d;        // dots[i][j] (A-layout for matmul 3)
    }
  }
  #pragma unroll
  for (int i = 0; i < 16; i++){
    #pragma unroll
    for (int o = 16; o; o >>= 1) dsum[i] += __shfl_xor(dsum[i], o);
  }
  __syncthreads();

  // ---- matmul 3: so = dots @ V ----
  f32x16_t ao[2] = {Z16, Z16};
  #pragma unroll
  for (int kb = 0; kb < 8; kb++){
    bf16x8 ad = *(const bf16x8*)&s_kp[mrow*136 + kb*16 + half*8];
    #pragma unroll
    for (int dt = 0; dt < 2; dt++){
      bf16x8 bv = *(const bf16x8*)&s_v[(dt*32 + col)*136 + kb*16 + half*8];
      ao[dt] = __builtin_amdgcn_mfma_f32_32x32x16_bf16(ad, bv, ao[dt], 0, 0, 0);
    }
  }

  // ---- epilogue: scatter to unsorted positions ----
  #pragma unroll
  for (int i = 0; i < 16; i++){
    int r = wid*32 + (i & 3) + 8*(i >> 2) + 4*half;
    int t = s_tq[r];
    o_g[(size_t)t*EDIM + col]      = ao[0][i];
    o_g[(size_t)t*EDIM + 32 + col] = ao[1][i];
    if (col == 0){ lse_g[t] = L[i]; dsm_g[t] = dsum[i]; }
  }
}

// ---------------- combine (logsumexp over hashes + Performer branch) ----------------
__global__ __launch_bounds__(256) void k_combine(char* __restrict__ ws){
  int b = blockIdx.x >> 6;
  int chunk = blockIdx.x & 63;
  int tid = threadIdx.x, lane = tid & 63, wid = tid >> 6;
  __shared__ float s_kv[MDIM*EDIM];
  __shared__ float s_ks[MDIM];
  __shared__ float s_qp[4][MDIM];
  const float* kv = (const float*)(ws+OFF_KV) + (size_t)b*MDIM*EDIM;
  for (int l = tid; l < MDIM*EDIM; l += 256) s_kv[l] = kv[l];
  if (tid < MDIM) s_ks[tid] = ((const float*)(ws+OFF_KSUM))[b*MDIM + tid];
  __syncthreads();
  const float* qp_g  = (const float*)(ws+OFF_QP) + (size_t)b*NSEQ*MDIM;
  const float* qls   = (const float*)(ws+OFF_QLS) + (size_t)b*NSEQ;
  const float* lse_g = (const float*)(ws+OFF_LSE);
  const float* dsm_g = (const float*)(ws+OFF_DSUM);
  const float* o_g   = (const float*)(ws+OFF_O);
  float* outn = (float*)(ws+OFF_OUTN);
  float klsb = decF(((const unsigned*)(ws+OFF_KLS))[b]);
  int bo = b >> 3, hh = b & 7;
  for (int it = 0; it < 16; it++){
    int t = chunk*64 + wid*16 + it;
    float qp0 = qp_g[(size_t)t*MDIM + lane];
    float qp1 = qp_g[(size_t)t*MDIM + 64 + lane];
    s_qp[wid][lane] = qp0; s_qp[wid][64 + lane] = qp1;
    __syncthreads();
    float qkv = 0.f;
    for (int m = 0; m < 128; m++) qkv = fmaf(s_qp[wid][m], s_kv[m*64 + lane], qkv);
    float qk1 = qp0*s_ks[lane] + qp1*s_ks[64 + lane];
    for (int o = 32; o; o >>= 1) qk1 += __shfl_xor(qk1, o);
    size_t pidx = (size_t)b*NSEQ + t;
    float l0 = lse_g[pidx], l1 = lse_g[(size_t)BH*NSEQ + pidx];
    float mx = fmaxf(l0, l1);
    float nls = mx + logf(expf(l0 - mx) + expf(l1 - mx));
    float p0 = expf(l0 - nls), p1 = expf(l1 - nls);
    float ps = expf(qls[t] + klsb - nls);
    float o0 = o_g[pidx*EDIM + lane];
    float o1 = o_g[((size_t)BH*NSEQ + pidx)*EDIM + lane];
    float ds0 = dsm_g[pidx], ds1 = dsm_g[(size_t)BH*NSEQ + pidx];
    float outv = o0*p0 + o1*p1 + qkv*ps;
    float nrm  = ds0*p0 + ds1*p1 + qk1*ps;
    outn[((size_t)bo*NSEQ + t)*DD + hh*EDIM + lane] = outv / fmaxf(nrm, 1e-6f);
    __syncthreads();
  }
}

// ---------------- final projection: out = outn @ W^T + b ----------------
__global__ __launch_bounds__(256) void k_final(const float* __restrict__ outW, const float* __restrict__ outB,
                                               const char* __restrict__ ws, float* __restrict__ out){
  __shared__ float WT[DD*65];      // [d][e], padded
  __shared__ float s_x[4][DD];
  int tid = threadIdx.x, lane = tid & 63, wid = tid >> 6;
  for (int l = tid; l < EDIM*DD; l += 256){
    int e = l >> 9, d = l & 511;
    WT[d*65 + e] = outW[l];
  }
  __syncthreads();
  const float* outn = (const float*)(ws+OFF_OUTN);
  for (int it = 0; it < 16; it++){
    int p = blockIdx.x*64 + wid*16 + it;
    const float* x = outn + (size_t)p*DD;
    #pragma unroll
    for (int c = 0; c < 8; c++) s_x[wid][c*64 + lane] = x[c*64 + lane];
    __syncthreads();
    float acc = 0.f;
    for (int d = 0; d < DD; d++) acc = fmaf(s_x[wid][d], WT[d*65 + lane], acc);
    out[(size_t)p*EDIM + lane] = acc + outB[lane];
    __syncthreads();
  }
}

extern "C" void kernel_launch(void* const* d_in, const int* in_sizes, int n_in,
                              void* d_out, int out_size, void* d_ws, size_t ws_size,
                              hipStream_t stream) {
  const float* query = (const float*)d_in[0];
  const float* key   = (const float*)d_in[1];
  const float* value = (const float*)d_in[2];
  const float* projW = (const float*)d_in[3];
  const float* alpha = (const float*)d_in[4];
  const float* beta  = (const float*)d_in[5];
  const float* outW  = (const float*)d_in[6];
  const float* outB  = (const float*)d_in[7];
  char* ws = (char*)d_ws;
  float* out = (float*)d_out;

  k_init <<<1024, 256, 0, stream>>>(ws);
  k_sumsq<<<512,  256, 0, stream>>>(query, key, ws);
  k_hash <<<512,  256, 0, stream>>>(query, key, alpha, beta, ws);
  k_sort <<<128,  512, 0, stream>>>(ws);
  k_featq<<<2048, 256, 0, stream>>>(query, projW, ws);
  k_featk<<<2048, 256, 0, stream>>>(key, projW, ws);
  k_expk <<<16384,256, 0, stream>>>(ws);
  k_kv   <<<256,  256, 0, stream>>>(value, ws);
  k_bucket<<<2048,256, 0, stream>>>(query, key, value, ws);
  k_combine<<<2048,256,0, stream>>>(ws);
  k_final<<<256,  256, 0, stream>>>(outW, outB, ws, out);
}